// Round 1
// baseline (679.520 us; speedup 1.0000x reference)
//
#include <hip/hip_runtime.h>

#define LSEQ 1024

__device__ __forceinline__ float gelu_f(float x){
    return 0.5f*x*(1.0f+erff(x*0.7071067811865476f));
}

// ---------------------------------------------------------------------------
// Fused GEMM: C[n] = A (M,K) x transform(B[n]) (K,1024); transform =
// optional groupnorm (from global stats) + optional affine + optional gelu.
// Also accumulates per-sample sum/sumsq of raw outputs into out_stats.
// ---------------------------------------------------------------------------
__global__ __launch_bounds__(256,2) void gemm_fused(
    const float* __restrict__ A,
    const float* __restrict__ B,
    float* __restrict__ C,
    const float* __restrict__ in_stats,
    const float* __restrict__ gw,
    const float* __restrict__ gb,
    float in_cnt_inv, int apply_gelu,
    int M, int K,
    float* __restrict__ out_stats)
{
    __shared__ float As[16][68];
    __shared__ float Bs[16][68];
    int tid = threadIdx.x;
    int n  = blockIdx.z;
    int n0 = blockIdx.x*64;
    int m0 = blockIdx.y*64;

    float mu=0.f, istd=1.f;
    if (in_stats){
        float s1 = in_stats[2*n], s2 = in_stats[2*n+1];
        mu = s1*in_cnt_inv;
        float var = s2*in_cnt_inv - mu*mu;
        istd = rsqrtf(var + 1e-5f);
    }

    const float* Bn = B + (size_t)n*K*LSEQ;
    int am = tid>>2, a4 = tid&3;      // A tile: 64 rows x 16 k
    int bk = tid>>4, b4 = tid&15;     // B tile: 16 k x 64 cols
    int ty = tid>>4, tx = tid&15;

    float acc[4][4];
    #pragma unroll
    for(int i=0;i<4;i++)
        #pragma unroll
        for(int j=0;j<4;j++) acc[i][j]=0.f;

    for(int k0=0;k0<K;k0+=16){
        float4 av = *(const float4*)(A + (size_t)(m0+am)*K + k0 + a4*4);
        As[a4*4+0][am]=av.x; As[a4*4+1][am]=av.y;
        As[a4*4+2][am]=av.z; As[a4*4+3][am]=av.w;

        int c = k0 + bk;
        float4 bv = *(const float4*)(Bn + (size_t)c*LSEQ + n0 + b4*4);
        float w_=1.f, bb_=0.f;
        if (gw){ w_=gw[c]; bb_=gb[c]; }
        float4 t;
        t.x=(bv.x-mu)*istd*w_+bb_;
        t.y=(bv.y-mu)*istd*w_+bb_;
        t.z=(bv.z-mu)*istd*w_+bb_;
        t.w=(bv.w-mu)*istd*w_+bb_;
        if (apply_gelu){ t.x=gelu_f(t.x); t.y=gelu_f(t.y); t.z=gelu_f(t.z); t.w=gelu_f(t.w); }
        *(float4*)&Bs[bk][b4*4] = t;
        __syncthreads();

        #pragma unroll
        for(int kk=0;kk<16;kk++){
            float4 a = *(const float4*)&As[kk][ty*4];
            float4 b = *(const float4*)&Bs[kk][tx*4];
            acc[0][0]+=a.x*b.x; acc[0][1]+=a.x*b.y; acc[0][2]+=a.x*b.z; acc[0][3]+=a.x*b.w;
            acc[1][0]+=a.y*b.x; acc[1][1]+=a.y*b.y; acc[1][2]+=a.y*b.z; acc[1][3]+=a.y*b.w;
            acc[2][0]+=a.z*b.x; acc[2][1]+=a.z*b.y; acc[2][2]+=a.z*b.z; acc[2][3]+=a.z*b.w;
            acc[3][0]+=a.w*b.x; acc[3][1]+=a.w*b.y; acc[3][2]+=a.w*b.z; acc[3][3]+=a.w*b.w;
        }
        __syncthreads();
    }

    size_t cbase = (size_t)n*M*LSEQ;
    float lsum=0.f, lsq=0.f;
    #pragma unroll
    for(int i=0;i<4;i++){
        float4 o;
        o.x=acc[i][0]; o.y=acc[i][1]; o.z=acc[i][2]; o.w=acc[i][3];
        *(float4*)(C + cbase + (size_t)(m0+ty*4+i)*LSEQ + n0 + tx*4) = o;
        lsum += o.x+o.y+o.z+o.w;
        lsq  += o.x*o.x+o.y*o.y+o.z*o.z+o.w*o.w;
    }
    float* scratch = &As[0][0];   // 1088 floats, free after last sync
    scratch[tid]     = lsum;
    scratch[256+tid] = lsq;
    __syncthreads();
    for(int s=128;s>0;s>>=1){
        if(tid<s){ scratch[tid]+=scratch[tid+s]; scratch[256+tid]+=scratch[256+tid+s]; }
        __syncthreads();
    }
    if(tid==0){
        atomicAdd(&out_stats[2*n],   scratch[0]);
        atomicAdd(&out_stats[2*n+1], scratch[256]);
    }
}

// ---------------------------------------------------------------------------
// Per-head analytic LayerNorm istd for the LxL logit map:
//   sum(s)  = sum_q . sum_k ;  sum(s^2) = sum_l q^T (sum_m k k^T) q
// ---------------------------------------------------------------------------
__global__ __launch_bounds__(256) void head_stats(
    const float* __restrict__ qkv,
    const float* __restrict__ s_qkv,
    const float* __restrict__ gq_w, const float* __restrict__ gq_b,
    float* __restrict__ istd_head)
{
    __shared__ float Ks[16*260];
    __shared__ float Ml[256];
    __shared__ float sumk[16];
    __shared__ float sumq[16];
    __shared__ double dred[256];

    int head = blockIdx.x;
    int n = head>>3, h = head&7;
    int tid = threadIdx.x;

    float s1 = s_qkv[2*n], s2v = s_qkv[2*n+1];
    float mu  = s1*(1.f/524288.f);
    float var = s2v*(1.f/524288.f) - mu*mu;
    float istd = rsqrtf(var + 1e-5f);

    const float* base = qkv + (size_t)n*512*LSEQ;
    int i_ = tid>>4, j_ = tid&15;
    float Mij = 0.f;
    float skp = 0.f;

    for(int m0=0;m0<1024;m0+=256){
        #pragma unroll
        for(int c=0;c<16;c++){
            int ch = 128 + h*16 + c;
            float x = base[(size_t)ch*LSEQ + m0 + tid];
            Ks[c*260+tid] = (x-mu)*istd*gq_w[ch]+gq_b[ch];
        }
        __syncthreads();
        for(int mm=0;mm<256;mm++)
            Mij += Ks[i_*260+mm]*Ks[j_*260+mm];
        if (tid<16){
            for(int mm=0;mm<256;mm++) skp += Ks[tid*260+mm];
        }
        __syncthreads();
    }
    Ml[tid] = Mij;
    if(tid<16){ sumk[tid]=skp; sumq[tid]=0.f; }
    __syncthreads();

    double S2p = 0.0;
    float sqp[16];
    #pragma unroll
    for(int c=0;c<16;c++) sqp[c]=0.f;

    for(int m0=0;m0<1024;m0+=256){
        #pragma unroll
        for(int c=0;c<16;c++){
            int ch = h*16 + c;
            float x = base[(size_t)ch*LSEQ + m0 + tid];
            Ks[c*260+tid] = (x-mu)*istd*gq_w[ch]+gq_b[ch];
        }
        __syncthreads();
        float q[16];
        #pragma unroll
        for(int c=0;c<16;c++) q[c]=Ks[c*260+tid];
        float accf = 0.f;
        #pragma unroll
        for(int i=0;i<16;i++){
            float t=0.f;
            #pragma unroll
            for(int j=0;j<16;j++) t += Ml[i*16+j]*q[j];
            accf += t*q[i];
        }
        S2p += (double)accf;
        #pragma unroll
        for(int c=0;c<16;c++) sqp[c]+=q[c];
        __syncthreads();
    }
    #pragma unroll
    for(int c=0;c<16;c++) atomicAdd(&sumq[c], sqp[c]);
    dred[tid] = S2p;
    __syncthreads();
    for(int s=128;s>0;s>>=1){
        if(tid<s) dred[tid]+=dred[tid+s];
        __syncthreads();
    }
    if(tid==0){
        double S1=0.0;
        for(int c=0;c<16;c++) S1 += (double)sumq[c]*(double)sumk[c];
        double cnt = 1048576.0;
        double mean = S1/cnt;
        double v2 = dred[0]/cnt - mean*mean;
        if(v2 < 0.0) v2 = 0.0;
        istd_head[head] = (float)(1.0/sqrt(v2 + 1e-5));
    }
}

// ---------------------------------------------------------------------------
// Attention: per block = (head, 256-row chunk of Q). K/V staged in LDS in
// 256-m chunks; all lanes walk m in lockstep => broadcast LDS reads.
// Two passes: rowmax, then exp/accumulate. Diagonal masked. Writes
// out[n, h*32+d, l] and accumulates per-sample sum/sumsq for the next LN.
// ---------------------------------------------------------------------------
__device__ __forceinline__ float dot16(const float q[16], const float* kr){
    const float4* k4 = (const float4*)kr;
    float4 k0=k4[0],k1=k4[1],k2=k4[2],k3=k4[3];
    return q[0]*k0.x+q[1]*k0.y+q[2]*k0.z+q[3]*k0.w
         + q[4]*k1.x+q[5]*k1.y+q[6]*k1.z+q[7]*k1.w
         + q[8]*k2.x+q[9]*k2.y+q[10]*k2.z+q[11]*k2.w
         + q[12]*k3.x+q[13]*k3.y+q[14]*k3.z+q[15]*k3.w;
}

__global__ __launch_bounds__(256,1) void attn_kernel(
    const float* __restrict__ qkv,
    const float* __restrict__ s_qkv,
    const float* __restrict__ gq_w, const float* __restrict__ gq_b,
    const float* __restrict__ istd_head,
    float* __restrict__ out,
    float* __restrict__ out_stats)
{
    __shared__ float Kc[256*20];   // 16 data + pad to 80B (16B-aligned rows)
    __shared__ float Vc[256*36];   // 32 data + pad to 144B
    int b = blockIdx.x;
    int head = b>>2, rb = b&3;
    int n = head>>3, h = head&7;
    int tid = threadIdx.x;
    int l = rb*256 + tid;

    const float* base = qkv + (size_t)n*512*LSEQ;
    float s1 = s_qkv[2*n], s2v = s_qkv[2*n+1];
    float mu  = s1*(1.f/524288.f);
    float var = s2v*(1.f/524288.f) - mu*mu;
    float istd = rsqrtf(var + 1e-5f);
    float ih = istd_head[head];

    float q[16];
    #pragma unroll
    for(int c=0;c<16;c++){
        int ch = h*16+c;
        float x = base[(size_t)ch*LSEQ + l];
        q[c] = ((x-mu)*istd*gq_w[ch]+gq_b[ch])*ih;   // pre-scale by logit-LN istd
    }

    // pass 1: row max of scaled scores
    float tmax = -3.0e38f;
    for(int m0=0;m0<1024;m0+=256){
        #pragma unroll
        for(int c=0;c<16;c++){
            int ch = 128+h*16+c;
            float x = base[(size_t)ch*LSEQ + m0 + tid];
            Kc[tid*20+c] = (x-mu)*istd*gq_w[ch]+gq_b[ch];
        }
        __syncthreads();
        for(int mm=0;mm<256;mm++){
            float s = dot16(q, Kc + mm*20);
            int m = m0+mm;
            s = (m==l) ? -3.0e38f : s;
            tmax = fmaxf(tmax, s);
        }
        __syncthreads();
    }

    // pass 2: exp + PV accumulate
    float o[32];
    #pragma unroll
    for(int d=0;d<32;d++) o[d]=0.f;
    float ssum = 0.f;

    for(int m0=0;m0<1024;m0+=256){
        #pragma unroll
        for(int c=0;c<16;c++){
            int ch = 128+h*16+c;
            float x = base[(size_t)ch*LSEQ + m0 + tid];
            Kc[tid*20+c] = (x-mu)*istd*gq_w[ch]+gq_b[ch];
        }
        #pragma unroll
        for(int d=0;d<32;d++){
            int ch = 256+h*32+d;
            float x = base[(size_t)ch*LSEQ + m0 + tid];
            Vc[tid*36+d] = (x-mu)*istd*gq_w[ch]+gq_b[ch];
        }
        __syncthreads();
        for(int mm=0;mm<256;mm++){
            float s = dot16(q, Kc + mm*20);
            int m = m0+mm;
            float p = (m==l) ? 0.f : __expf(s - tmax);
            ssum += p;
            const float4* vr = (const float4*)(Vc + mm*36);
            #pragma unroll
            for(int dq=0;dq<8;dq++){
                float4 v = vr[dq];
                o[dq*4+0] += p*v.x;
                o[dq*4+1] += p*v.y;
                o[dq*4+2] += p*v.z;
                o[dq*4+3] += p*v.w;
            }
        }
        __syncthreads();
    }

    float inv = 1.f/ssum;
    float lsum=0.f, lsq=0.f;
    #pragma unroll
    for(int d=0;d<32;d++){
        float y = o[d]*inv;
        out[(size_t)n*262144 + (size_t)(h*32+d)*LSEQ + l] = y;
        lsum += y; lsq += y*y;
    }
    float* red = Kc;   // free after final sync
    red[tid]=lsum; red[256+tid]=lsq;
    __syncthreads();
    for(int s=128;s>0;s>>=1){
        if(tid<s){ red[tid]+=red[tid+s]; red[256+tid]+=red[256+tid+s]; }
        __syncthreads();
    }
    if(tid==0){
        atomicAdd(&out_stats[2*n],   red[0]);
        atomicAdd(&out_stats[2*n+1], red[256]);
    }
}

// ---------------------------------------------------------------------------
// out = gelu(resid + groupnorm(x)) elementwise; c = channel of element.
// ---------------------------------------------------------------------------
__global__ __launch_bounds__(256) void ew_resid(
    const float* __restrict__ resid, const float* __restrict__ x,
    const float* __restrict__ stats,
    const float* __restrict__ gw, const float* __restrict__ gb,
    float cnt_inv, float* __restrict__ out)
{
    int idx = blockIdx.x*256 + threadIdx.x;   // float4 index
    int n = idx >> 16;                        // 65536 float4 per sample
    int c = (idx >> 8) & 255;
    float ss = stats[2*n], s2 = stats[2*n+1];
    float mu = ss*cnt_inv;
    float var = s2*cnt_inv - mu*mu;
    float istd = rsqrtf(var + 1e-5f);
    float w_ = gw[c], b_ = gb[c];
    float4 xv = ((const float4*)x)[idx];
    float4 rv = ((const float4*)resid)[idx];
    float4 ov;
    ov.x = gelu_f(rv.x + ((xv.x-mu)*istd*w_+b_));
    ov.y = gelu_f(rv.y + ((xv.y-mu)*istd*w_+b_));
    ov.z = gelu_f(rv.z + ((xv.z-mu)*istd*w_+b_));
    ov.w = gelu_f(rv.w + ((xv.w-mu)*istd*w_+b_));
    ((float4*)out)[idx] = ov;
}

// ---------------------------------------------------------------------------
extern "C" void kernel_launch(void* const* d_in, const int* in_sizes, int n_in,
                              void* d_out, int out_size, void* d_ws, size_t ws_size,
                              hipStream_t stream) {
    const float* f     = (const float*)d_in[0];
    const float* w_z   = (const float*)d_in[1];
    const float* gz_w  = (const float*)d_in[2];
    const float* gz_b  = (const float*)d_in[3];
    const float* w_qkv = (const float*)d_in[4];
    const float* gq_w  = (const float*)d_in[5];
    const float* gq_b  = (const float*)d_in[6];
    const float* w_out = (const float*)d_in[7];
    const float* go_w  = (const float*)d_in[8];
    const float* go_b  = (const float*)d_in[9];
    const float* w_f1  = (const float*)d_in[10];
    const float* g1_w  = (const float*)d_in[11];
    const float* g1_b  = (const float*)d_in[12];
    const float* w_f2  = (const float*)d_in[13];
    const float* g2_w  = (const float*)d_in[14];
    const float* g2_b  = (const float*)d_in[15];

    float* ws = (float*)d_ws;
    float* stats = ws;                 // 256 floats
    float* s_z    = stats + 0;
    float* s_qkv  = stats + 16;
    float* s_attn = stats + 32;
    float* s_x    = stats + 48;
    float* s_h1   = stats + 64;
    float* s_h2   = stats + 80;
    float* istdh  = stats + 96;        // 64
    const size_t SM = (size_t)256*1024;   // per-sample 256-ch tensor
    float* buf0 = ws + 256;            // 8*SM  : z0 -> attn_out -> f1 (buf3 alias)
    float* buf1 = buf0 + 8*SM;         // 8*2SM : qkv -> h1pre
    float* buf2 = buf1 + 16*SM;        // 8*SM  : x -> h2pre
    float* buf3 = buf0;                // f1 aliases buf0 (dead after K4)
    float* outp = (float*)d_out;

    hipMemsetAsync(stats, 0, 256*sizeof(float), stream);

    dim3 blk(256);
    // z0 = w_z @ gelu(f)
    gemm_fused<<<dim3(16,4,8),blk,0,stream>>>(w_z, f, buf0,
        nullptr, nullptr, nullptr, 0.f, 1, 256, 256, s_z);
    // qkv = w_qkv @ gelu(gn(z0))
    gemm_fused<<<dim3(16,8,8),blk,0,stream>>>(w_qkv, buf0, buf1,
        s_z, gz_w, gz_b, 1.f/262144.f, 1, 512, 256, s_qkv);
    // analytic per-head logit-LN istd
    head_stats<<<64,blk,0,stream>>>(buf1, s_qkv, gq_w, gq_b, istdh);
    // attention -> attn_out (overwrites z0)
    attn_kernel<<<256,blk,0,stream>>>(buf1, s_qkv, gq_w, gq_b, istdh, buf0, s_attn);
    // x = w_out @ gelu(ln(attn_out))
    gemm_fused<<<dim3(16,4,8),blk,0,stream>>>(w_out, buf0, buf2,
        s_attn, nullptr, nullptr, 1.f/262144.f, 1, 256, 256, s_x);
    // f1 = gelu(f + gn_go(x))   (writes over attn_out region)
    ew_resid<<<2048,blk,0,stream>>>(f, buf2, s_x, go_w, go_b, 1.f/262144.f, buf3);
    // h1 = w_ffn1 @ f1
    gemm_fused<<<dim3(16,8,8),blk,0,stream>>>(w_f1, buf3, buf1,
        nullptr, nullptr, nullptr, 0.f, 0, 512, 256, s_h1);
    // h2 = w_ffn2 @ gelu(gn_g1(h1))
    gemm_fused<<<dim3(16,4,8),blk,0,stream>>>(w_f2, buf1, buf2,
        s_h1, g1_w, g1_b, 1.f/524288.f, 1, 256, 512, s_h2);
    // out = gelu(f1 + gn_g2(h2))
    ew_resid<<<2048,blk,0,stream>>>(buf3, buf2, s_h2, g2_w, g2_b, 1.f/262144.f, outp);
}

// Round 2
// 632.302 us; speedup vs baseline: 1.0747x; 1.0747x over previous
//
#include <hip/hip_runtime.h>

#define LSEQ 1024

__device__ __forceinline__ float gelu_f(float x){
    return 0.5f*x*(1.0f+erff(x*0.7071067811865476f));
}

// ---------------------------------------------------------------------------
// Fused GEMM: C[n] = A (M,K) x transform(B[n]) (K,1024); transform =
// optional groupnorm (from global stats) + optional affine + optional gelu.
// Also accumulates per-sample sum/sumsq of raw outputs into out_stats.
// ---------------------------------------------------------------------------
__global__ __launch_bounds__(256,2) void gemm_fused(
    const float* __restrict__ A,
    const float* __restrict__ B,
    float* __restrict__ C,
    const float* __restrict__ in_stats,
    const float* __restrict__ gw,
    const float* __restrict__ gb,
    float in_cnt_inv, int apply_gelu,
    int M, int K,
    float* __restrict__ out_stats)
{
    __shared__ float As[16][68];
    __shared__ float Bs[16][68];
    int tid = threadIdx.x;
    int n  = blockIdx.z;
    int n0 = blockIdx.x*64;
    int m0 = blockIdx.y*64;

    float mu=0.f, istd=1.f;
    if (in_stats){
        float s1 = in_stats[2*n], s2 = in_stats[2*n+1];
        mu = s1*in_cnt_inv;
        float var = s2*in_cnt_inv - mu*mu;
        istd = rsqrtf(var + 1e-5f);
    }

    const float* Bn = B + (size_t)n*K*LSEQ;
    int am = tid>>2, a4 = tid&3;      // A tile: 64 rows x 16 k
    int bk = tid>>4, b4 = tid&15;     // B tile: 16 k x 64 cols
    int ty = tid>>4, tx = tid&15;

    float acc[4][4];
    #pragma unroll
    for(int i=0;i<4;i++)
        #pragma unroll
        for(int j=0;j<4;j++) acc[i][j]=0.f;

    for(int k0=0;k0<K;k0+=16){
        float4 av = *(const float4*)(A + (size_t)(m0+am)*K + k0 + a4*4);
        As[a4*4+0][am]=av.x; As[a4*4+1][am]=av.y;
        As[a4*4+2][am]=av.z; As[a4*4+3][am]=av.w;

        int c = k0 + bk;
        float4 bv = *(const float4*)(Bn + (size_t)c*LSEQ + n0 + b4*4);
        float w_=1.f, bb_=0.f;
        if (gw){ w_=gw[c]; bb_=gb[c]; }
        float4 t;
        t.x=(bv.x-mu)*istd*w_+bb_;
        t.y=(bv.y-mu)*istd*w_+bb_;
        t.z=(bv.z-mu)*istd*w_+bb_;
        t.w=(bv.w-mu)*istd*w_+bb_;
        if (apply_gelu){ t.x=gelu_f(t.x); t.y=gelu_f(t.y); t.z=gelu_f(t.z); t.w=gelu_f(t.w); }
        *(float4*)&Bs[bk][b4*4] = t;
        __syncthreads();

        #pragma unroll
        for(int kk=0;kk<16;kk++){
            float4 a = *(const float4*)&As[kk][ty*4];
            float4 b = *(const float4*)&Bs[kk][tx*4];
            acc[0][0]+=a.x*b.x; acc[0][1]+=a.x*b.y; acc[0][2]+=a.x*b.z; acc[0][3]+=a.x*b.w;
            acc[1][0]+=a.y*b.x; acc[1][1]+=a.y*b.y; acc[1][2]+=a.y*b.z; acc[1][3]+=a.y*b.w;
            acc[2][0]+=a.z*b.x; acc[2][1]+=a.z*b.y; acc[2][2]+=a.z*b.z; acc[2][3]+=a.z*b.w;
            acc[3][0]+=a.w*b.x; acc[3][1]+=a.w*b.y; acc[3][2]+=a.w*b.z; acc[3][3]+=a.w*b.w;
        }
        __syncthreads();
    }

    size_t cbase = (size_t)n*M*LSEQ;
    float lsum=0.f, lsq=0.f;
    #pragma unroll
    for(int i=0;i<4;i++){
        float4 o;
        o.x=acc[i][0]; o.y=acc[i][1]; o.z=acc[i][2]; o.w=acc[i][3];
        *(float4*)(C + cbase + (size_t)(m0+ty*4+i)*LSEQ + n0 + tx*4) = o;
        lsum += o.x+o.y+o.z+o.w;
        lsq  += o.x*o.x+o.y*o.y+o.z*o.z+o.w*o.w;
    }
    float* scratch = &As[0][0];   // 1088 floats, free after last sync
    scratch[tid]     = lsum;
    scratch[256+tid] = lsq;
    __syncthreads();
    for(int s=128;s>0;s>>=1){
        if(tid<s){ scratch[tid]+=scratch[tid+s]; scratch[256+tid]+=scratch[256+tid+s]; }
        __syncthreads();
    }
    if(tid==0){
        atomicAdd(&out_stats[2*n],   scratch[0]);
        atomicAdd(&out_stats[2*n+1], scratch[256]);
    }
}

// ---------------------------------------------------------------------------
// Per-head analytic LayerNorm istd for the LxL logit map:
//   sum(s)  = sum_q . sum_k ;  sum(s^2) = sum_l q^T (sum_m k k^T) q
// ---------------------------------------------------------------------------
__global__ __launch_bounds__(256) void head_stats(
    const float* __restrict__ qkv,
    const float* __restrict__ s_qkv,
    const float* __restrict__ gq_w, const float* __restrict__ gq_b,
    float* __restrict__ istd_head)
{
    __shared__ float Ks[16*260];
    __shared__ float Ml[256];
    __shared__ float sumk[16];
    __shared__ float sumq[16];
    __shared__ double dred[256];

    int head = blockIdx.x;
    int n = head>>3, h = head&7;
    int tid = threadIdx.x;

    float s1 = s_qkv[2*n], s2v = s_qkv[2*n+1];
    float mu  = s1*(1.f/524288.f);
    float var = s2v*(1.f/524288.f) - mu*mu;
    float istd = rsqrtf(var + 1e-5f);

    const float* base = qkv + (size_t)n*512*LSEQ;
    int i_ = tid>>4, j_ = tid&15;
    float Mij = 0.f;
    float skp = 0.f;

    for(int m0=0;m0<1024;m0+=256){
        #pragma unroll
        for(int c=0;c<16;c++){
            int ch = 128 + h*16 + c;
            float x = base[(size_t)ch*LSEQ + m0 + tid];
            Ks[c*260+tid] = (x-mu)*istd*gq_w[ch]+gq_b[ch];
        }
        __syncthreads();
        for(int mm=0;mm<256;mm++)
            Mij += Ks[i_*260+mm]*Ks[j_*260+mm];
        if (tid<16){
            for(int mm=0;mm<256;mm++) skp += Ks[tid*260+mm];
        }
        __syncthreads();
    }
    Ml[tid] = Mij;
    if(tid<16){ sumk[tid]=skp; sumq[tid]=0.f; }
    __syncthreads();

    double S2p = 0.0;
    float sqp[16];
    #pragma unroll
    for(int c=0;c<16;c++) sqp[c]=0.f;

    for(int m0=0;m0<1024;m0+=256){
        #pragma unroll
        for(int c=0;c<16;c++){
            int ch = h*16 + c;
            float x = base[(size_t)ch*LSEQ + m0 + tid];
            Ks[c*260+tid] = (x-mu)*istd*gq_w[ch]+gq_b[ch];
        }
        __syncthreads();
        float q[16];
        #pragma unroll
        for(int c=0;c<16;c++) q[c]=Ks[c*260+tid];
        float accf = 0.f;
        #pragma unroll
        for(int i=0;i<16;i++){
            float t=0.f;
            #pragma unroll
            for(int j=0;j<16;j++) t += Ml[i*16+j]*q[j];
            accf += t*q[i];
        }
        S2p += (double)accf;
        #pragma unroll
        for(int c=0;c<16;c++) sqp[c]+=q[c];
        __syncthreads();
    }
    #pragma unroll
    for(int c=0;c<16;c++) atomicAdd(&sumq[c], sqp[c]);
    dred[tid] = S2p;
    __syncthreads();
    for(int s=128;s>0;s>>=1){
        if(tid<s) dred[tid]+=dred[tid+s];
        __syncthreads();
    }
    if(tid==0){
        double S1=0.0;
        for(int c=0;c<16;c++) S1 += (double)sumq[c]*(double)sumk[c];
        double cnt = 1048576.0;
        double mean = S1/cnt;
        double v2 = dred[0]/cnt - mean*mean;
        if(v2 < 0.0) v2 = 0.0;
        istd_head[head] = (float)(1.0/sqrt(v2 + 1e-5));
    }
}

// ---------------------------------------------------------------------------
// Attention v2: register-blocked. Block = (head, 128-row chunk). Thread
// (rg, ms): owns 4 Q rows (rg*4..+3), covers m = ms + 8*j within each staged
// 256-m K/V chunk. One K/V LDS row read feeds 4 rows of FLOP (4x FLOP/byte
// vs v1). Partial max/sum/o merged across the 8 ms lanes (same wave) via
// __shfl_xor. Output restaged through LDS for coalesced global writes.
// ---------------------------------------------------------------------------
__device__ __forceinline__ float dot16r(const float q[16], const float4 k0,
    const float4 k1, const float4 k2, const float4 k3){
    return q[0]*k0.x+q[1]*k0.y+q[2]*k0.z+q[3]*k0.w
         + q[4]*k1.x+q[5]*k1.y+q[6]*k1.z+q[7]*k1.w
         + q[8]*k2.x+q[9]*k2.y+q[10]*k2.z+q[11]*k2.w
         + q[12]*k3.x+q[13]*k3.y+q[14]*k3.z+q[15]*k3.w;
}

__global__ __launch_bounds__(256,2) void attn_kernel(
    const float* __restrict__ qkv,
    const float* __restrict__ s_qkv,
    const float* __restrict__ gq_w, const float* __restrict__ gq_b,
    const float* __restrict__ istd_head,
    float* __restrict__ out,
    float* __restrict__ out_stats)
{
    __shared__ float Kc[256*20];   // 16 data + pad
    __shared__ float Vc[256*36];   // 32 data + pad
    int b = blockIdx.x;
    int head = b>>3, rb = b&7;
    int n = head>>3, h = head&7;
    int tid = threadIdx.x;
    int rg = tid>>3, ms = tid&7;   // ms lanes are wave lane bits 0..2
    int l0 = rb*128;
    int lr = l0 + rg*4;            // first of this thread's 4 rows

    const float* base = qkv + (size_t)n*512*LSEQ;
    float s1 = s_qkv[2*n], s2v = s_qkv[2*n+1];
    float mu  = s1*(1.f/524288.f);
    float var = s2v*(1.f/524288.f) - mu*mu;
    float istd = rsqrtf(var + 1e-5f);
    float ih = istd_head[head];

    float q[4][16];
    #pragma unroll
    for(int c=0;c<16;c++){
        int ch = h*16+c;
        float w_ = gq_w[ch]*istd*ih, b_ = (gq_b[ch]-mu*istd*gq_w[ch])*ih;
        #pragma unroll
        for(int r=0;r<4;r++){
            float x = base[(size_t)ch*LSEQ + lr + r];
            q[r][c] = x*w_ + b_;   // == ((x-mu)*istd*gw+gb)*ih
        }
    }

    // ---- pass 1: per-row max of scaled scores ----
    float tmax[4];
    #pragma unroll
    for(int r=0;r<4;r++) tmax[r] = -3.0e38f;

    for(int m0=0;m0<1024;m0+=256){
        #pragma unroll
        for(int c=0;c<16;c++){
            int ch = 128+h*16+c;
            float x = base[(size_t)ch*LSEQ + m0 + tid];
            Kc[tid*20+c] = (x-mu)*istd*gq_w[ch]+gq_b[ch];
        }
        __syncthreads();
        for(int j=0;j<32;j++){
            int mm = ms + 8*j;
            int m = m0 + mm;
            const float4* k4 = (const float4*)(Kc + mm*20);
            float4 k0=k4[0],k1=k4[1],k2=k4[2],k3=k4[3];
            #pragma unroll
            for(int r=0;r<4;r++){
                float s = dot16r(q[r],k0,k1,k2,k3);
                s = (m==lr+r) ? -3.0e38f : s;
                tmax[r] = fmaxf(tmax[r], s);
            }
        }
        __syncthreads();
    }
    // merge max across the 8 ms lanes (butterfly)
    #pragma unroll
    for(int r=0;r<4;r++){
        tmax[r] = fmaxf(tmax[r], __shfl_xor(tmax[r],1));
        tmax[r] = fmaxf(tmax[r], __shfl_xor(tmax[r],2));
        tmax[r] = fmaxf(tmax[r], __shfl_xor(tmax[r],4));
    }

    // ---- pass 2: exp + PV accumulate ----
    float o[4][32];
    #pragma unroll
    for(int r=0;r<4;r++)
        #pragma unroll
        for(int d=0;d<32;d++) o[r][d]=0.f;
    float ssum[4] = {0.f,0.f,0.f,0.f};

    for(int m0=0;m0<1024;m0+=256){
        #pragma unroll
        for(int c=0;c<16;c++){
            int ch = 128+h*16+c;
            float x = base[(size_t)ch*LSEQ + m0 + tid];
            Kc[tid*20+c] = (x-mu)*istd*gq_w[ch]+gq_b[ch];
        }
        #pragma unroll
        for(int d=0;d<32;d++){
            int ch = 256+h*32+d;
            float x = base[(size_t)ch*LSEQ + m0 + tid];
            Vc[tid*36+d] = (x-mu)*istd*gq_w[ch]+gq_b[ch];
        }
        __syncthreads();
        for(int j=0;j<32;j++){
            int mm = ms + 8*j;
            int m = m0 + mm;
            const float4* k4 = (const float4*)(Kc + mm*20);
            float4 k0=k4[0],k1=k4[1],k2=k4[2],k3=k4[3];
            float p[4];
            #pragma unroll
            for(int r=0;r<4;r++){
                float s = dot16r(q[r],k0,k1,k2,k3);
                float pv = __expf(s - tmax[r]);
                pv = (m==lr+r) ? 0.f : pv;
                p[r]=pv; ssum[r]+=pv;
            }
            const float4* vr = (const float4*)(Vc + mm*36);
            #pragma unroll
            for(int dq=0;dq<8;dq++){
                float4 v = vr[dq];
                #pragma unroll
                for(int r=0;r<4;r++){
                    o[r][dq*4+0] += p[r]*v.x;
                    o[r][dq*4+1] += p[r]*v.y;
                    o[r][dq*4+2] += p[r]*v.z;
                    o[r][dq*4+3] += p[r]*v.w;
                }
            }
        }
        __syncthreads();
    }

    // merge partial sums and o across ms lanes (butterfly => all lanes get total)
    #pragma unroll
    for(int r=0;r<4;r++){
        ssum[r] += __shfl_xor(ssum[r],1);
        ssum[r] += __shfl_xor(ssum[r],2);
        ssum[r] += __shfl_xor(ssum[r],4);
    }
    #pragma unroll
    for(int r=0;r<4;r++)
        #pragma unroll
        for(int d=0;d<32;d++){
            float t = o[r][d];
            t += __shfl_xor(t,1);
            t += __shfl_xor(t,2);
            t += __shfl_xor(t,4);
            o[r][d] = t;
        }

    // stage normalized output to LDS: osm[row][d] padded to 33
    float* osm = Kc;  // 128*33+32 floats = 17KB <= 20KB
    {
        float inv[4];
        #pragma unroll
        for(int r=0;r<4;r++) inv[r] = 1.f/ssum[r];
        #pragma unroll
        for(int dd=0;dd<4;dd++){
            int d = ms*4+dd;
            #pragma unroll
            for(int r=0;r<4;r++)
                osm[(rg*4+r)*33 + d] = o[r][d]*inv[r];
        }
    }
    __syncthreads();

    // coalesced global write + stats
    float lsum=0.f, lsq=0.f;
    #pragma unroll
    for(int t=0;t<16;t++){
        int idx = t*256 + tid;
        int d = idx>>7, ll = idx&127;
        float y = osm[ll*33 + d];
        out[(size_t)n*262144 + (size_t)(h*32+d)*LSEQ + l0+ll] = y;
        lsum += y; lsq += y*y;
    }
    float* red = Vc;
    red[tid]=lsum; red[256+tid]=lsq;
    __syncthreads();
    for(int s=128;s>0;s>>=1){
        if(tid<s){ red[tid]+=red[tid+s]; red[256+tid]+=red[256+tid+s]; }
        __syncthreads();
    }
    if(tid==0){
        atomicAdd(&out_stats[2*n],   red[0]);
        atomicAdd(&out_stats[2*n+1], red[256]);
    }
}

// ---------------------------------------------------------------------------
// out = gelu(resid + groupnorm(x)) elementwise; c = channel of element.
// ---------------------------------------------------------------------------
__global__ __launch_bounds__(256) void ew_resid(
    const float* __restrict__ resid, const float* __restrict__ x,
    const float* __restrict__ stats,
    const float* __restrict__ gw, const float* __restrict__ gb,
    float cnt_inv, float* __restrict__ out)
{
    int idx = blockIdx.x*256 + threadIdx.x;   // float4 index
    int n = idx >> 16;                        // 65536 float4 per sample
    int c = (idx >> 8) & 255;
    float ss = stats[2*n], s2 = stats[2*n+1];
    float mu = ss*cnt_inv;
    float var = s2*cnt_inv - mu*mu;
    float istd = rsqrtf(var + 1e-5f);
    float w_ = gw[c], b_ = gb[c];
    float4 xv = ((const float4*)x)[idx];
    float4 rv = ((const float4*)resid)[idx];
    float4 ov;
    ov.x = gelu_f(rv.x + ((xv.x-mu)*istd*w_+b_));
    ov.y = gelu_f(rv.y + ((xv.y-mu)*istd*w_+b_));
    ov.z = gelu_f(rv.z + ((xv.z-mu)*istd*w_+b_));
    ov.w = gelu_f(rv.w + ((xv.w-mu)*istd*w_+b_));
    ((float4*)out)[idx] = ov;
}

// ---------------------------------------------------------------------------
extern "C" void kernel_launch(void* const* d_in, const int* in_sizes, int n_in,
                              void* d_out, int out_size, void* d_ws, size_t ws_size,
                              hipStream_t stream) {
    const float* f     = (const float*)d_in[0];
    const float* w_z   = (const float*)d_in[1];
    const float* gz_w  = (const float*)d_in[2];
    const float* gz_b  = (const float*)d_in[3];
    const float* w_qkv = (const float*)d_in[4];
    const float* gq_w  = (const float*)d_in[5];
    const float* gq_b  = (const float*)d_in[6];
    const float* w_out = (const float*)d_in[7];
    const float* go_w  = (const float*)d_in[8];
    const float* go_b  = (const float*)d_in[9];
    const float* w_f1  = (const float*)d_in[10];
    const float* g1_w  = (const float*)d_in[11];
    const float* g1_b  = (const float*)d_in[12];
    const float* w_f2  = (const float*)d_in[13];
    const float* g2_w  = (const float*)d_in[14];
    const float* g2_b  = (const float*)d_in[15];

    float* ws = (float*)d_ws;
    float* stats = ws;                 // 256 floats
    float* s_z    = stats + 0;
    float* s_qkv  = stats + 16;
    float* s_attn = stats + 32;
    float* s_x    = stats + 48;
    float* s_h1   = stats + 64;
    float* s_h2   = stats + 80;
    float* istdh  = stats + 96;        // 64
    const size_t SM = (size_t)256*1024;   // per-sample 256-ch tensor
    float* buf0 = ws + 256;            // 8*SM  : z0 -> attn_out -> f1 (buf3 alias)
    float* buf1 = buf0 + 8*SM;         // 8*2SM : qkv -> h1pre
    float* buf2 = buf1 + 16*SM;        // 8*SM  : x -> h2pre
    float* buf3 = buf0;                // f1 aliases buf0 (dead after K4)
    float* outp = (float*)d_out;

    hipMemsetAsync(stats, 0, 256*sizeof(float), stream);

    dim3 blk(256);
    // z0 = w_z @ gelu(f)
    gemm_fused<<<dim3(16,4,8),blk,0,stream>>>(w_z, f, buf0,
        nullptr, nullptr, nullptr, 0.f, 1, 256, 256, s_z);
    // qkv = w_qkv @ gelu(gn(z0))
    gemm_fused<<<dim3(16,8,8),blk,0,stream>>>(w_qkv, buf0, buf1,
        s_z, gz_w, gz_b, 1.f/262144.f, 1, 512, 256, s_qkv);
    // analytic per-head logit-LN istd
    head_stats<<<64,blk,0,stream>>>(buf1, s_qkv, gq_w, gq_b, istdh);
    // attention -> attn_out (overwrites z0)
    attn_kernel<<<512,blk,0,stream>>>(buf1, s_qkv, gq_w, gq_b, istdh, buf0, s_attn);
    // x = w_out @ gelu(ln(attn_out))
    gemm_fused<<<dim3(16,4,8),blk,0,stream>>>(w_out, buf0, buf2,
        s_attn, nullptr, nullptr, 1.f/262144.f, 1, 256, 256, s_x);
    // f1 = gelu(f + gn_go(x))   (writes over attn_out region)
    ew_resid<<<2048,blk,0,stream>>>(f, buf2, s_x, go_w, go_b, 1.f/262144.f, buf3);
    // h1 = w_ffn1 @ f1
    gemm_fused<<<dim3(16,8,8),blk,0,stream>>>(w_f1, buf3, buf1,
        nullptr, nullptr, nullptr, 0.f, 0, 512, 256, s_h1);
    // h2 = w_ffn2 @ gelu(gn_g1(h1))
    gemm_fused<<<dim3(16,4,8),blk,0,stream>>>(w_f2, buf1, buf2,
        s_h1, g1_w, g1_b, 1.f/524288.f, 1, 256, 512, s_h2);
    // out = gelu(f1 + gn_g2(h2))
    ew_resid<<<2048,blk,0,stream>>>(buf3, buf2, s_h2, g2_w, g2_b, 1.f/262144.f, outp);
}

// Round 3
// 538.047 us; speedup vs baseline: 1.2629x; 1.1752x over previous
//
#include <hip/hip_runtime.h>

#define LSEQ 1024

__device__ __forceinline__ float gelu_f(float x){
    return 0.5f*x*(1.0f+erff(x*0.7071067811865476f));
}

// ---------------------------------------------------------------------------
// Fused GEMM: C[n] = A (M,K) x transform(B[n]) (K,1024); transform =
// optional groupnorm (from global stats) + optional affine + optional gelu.
// Also accumulates per-sample sum/sumsq of raw outputs into out_stats.
// ---------------------------------------------------------------------------
__global__ __launch_bounds__(256,2) void gemm_fused(
    const float* __restrict__ A,
    const float* __restrict__ B,
    float* __restrict__ C,
    const float* __restrict__ in_stats,
    const float* __restrict__ gw,
    const float* __restrict__ gb,
    float in_cnt_inv, int apply_gelu,
    int M, int K,
    float* __restrict__ out_stats)
{
    __shared__ float As[16][68];
    __shared__ float Bs[16][68];
    int tid = threadIdx.x;
    int n  = blockIdx.z;
    int n0 = blockIdx.x*64;
    int m0 = blockIdx.y*64;

    float mu=0.f, istd=1.f;
    if (in_stats){
        float s1 = in_stats[2*n], s2 = in_stats[2*n+1];
        mu = s1*in_cnt_inv;
        float var = s2*in_cnt_inv - mu*mu;
        istd = rsqrtf(var + 1e-5f);
    }

    const float* Bn = B + (size_t)n*K*LSEQ;
    int am = tid>>2, a4 = tid&3;      // A tile: 64 rows x 16 k
    int bk = tid>>4, b4 = tid&15;     // B tile: 16 k x 64 cols
    int ty = tid>>4, tx = tid&15;

    float acc[4][4];
    #pragma unroll
    for(int i=0;i<4;i++)
        #pragma unroll
        for(int j=0;j<4;j++) acc[i][j]=0.f;

    for(int k0=0;k0<K;k0+=16){
        float4 av = *(const float4*)(A + (size_t)(m0+am)*K + k0 + a4*4);
        As[a4*4+0][am]=av.x; As[a4*4+1][am]=av.y;
        As[a4*4+2][am]=av.z; As[a4*4+3][am]=av.w;

        int c = k0 + bk;
        float4 bv = *(const float4*)(Bn + (size_t)c*LSEQ + n0 + b4*4);
        float w_=1.f, bb_=0.f;
        if (gw){ w_=gw[c]; bb_=gb[c]; }
        float4 t;
        t.x=(bv.x-mu)*istd*w_+bb_;
        t.y=(bv.y-mu)*istd*w_+bb_;
        t.z=(bv.z-mu)*istd*w_+bb_;
        t.w=(bv.w-mu)*istd*w_+bb_;
        if (apply_gelu){ t.x=gelu_f(t.x); t.y=gelu_f(t.y); t.z=gelu_f(t.z); t.w=gelu_f(t.w); }
        *(float4*)&Bs[bk][b4*4] = t;
        __syncthreads();

        #pragma unroll
        for(int kk=0;kk<16;kk++){
            float4 a = *(const float4*)&As[kk][ty*4];
            float4 b = *(const float4*)&Bs[kk][tx*4];
            acc[0][0]+=a.x*b.x; acc[0][1]+=a.x*b.y; acc[0][2]+=a.x*b.z; acc[0][3]+=a.x*b.w;
            acc[1][0]+=a.y*b.x; acc[1][1]+=a.y*b.y; acc[1][2]+=a.y*b.z; acc[1][3]+=a.y*b.w;
            acc[2][0]+=a.z*b.x; acc[2][1]+=a.z*b.y; acc[2][2]+=a.z*b.z; acc[2][3]+=a.z*b.w;
            acc[3][0]+=a.w*b.x; acc[3][1]+=a.w*b.y; acc[3][2]+=a.w*b.z; acc[3][3]+=a.w*b.w;
        }
        __syncthreads();
    }

    size_t cbase = (size_t)n*M*LSEQ;
    float lsum=0.f, lsq=0.f;
    #pragma unroll
    for(int i=0;i<4;i++){
        float4 o;
        o.x=acc[i][0]; o.y=acc[i][1]; o.z=acc[i][2]; o.w=acc[i][3];
        *(float4*)(C + cbase + (size_t)(m0+ty*4+i)*LSEQ + n0 + tx*4) = o;
        lsum += o.x+o.y+o.z+o.w;
        lsq  += o.x*o.x+o.y*o.y+o.z*o.z+o.w*o.w;
    }
    float* scratch = &As[0][0];   // 1088 floats, free after last sync
    scratch[tid]     = lsum;
    scratch[256+tid] = lsq;
    __syncthreads();
    for(int s=128;s>0;s>>=1){
        if(tid<s){ scratch[tid]+=scratch[tid+s]; scratch[256+tid]+=scratch[256+tid+s]; }
        __syncthreads();
    }
    if(tid==0){
        atomicAdd(&out_stats[2*n],   scratch[0]);
        atomicAdd(&out_stats[2*n+1], scratch[256]);
    }
}

// ---------------------------------------------------------------------------
// Per-head analytic LayerNorm istd for the LxL logit map:
//   sum(s)  = sum_q . sum_k ;  sum(s^2) = sum_l q^T (sum_m k k^T) q
// ---------------------------------------------------------------------------
__global__ __launch_bounds__(256) void head_stats(
    const float* __restrict__ qkv,
    const float* __restrict__ s_qkv,
    const float* __restrict__ gq_w, const float* __restrict__ gq_b,
    float* __restrict__ istd_head)
{
    __shared__ float Ks[16*260];
    __shared__ float Ml[256];
    __shared__ float sumk[16];
    __shared__ float sumq[16];
    __shared__ double dred[256];

    int head = blockIdx.x;
    int n = head>>3, h = head&7;
    int tid = threadIdx.x;

    float s1 = s_qkv[2*n], s2v = s_qkv[2*n+1];
    float mu  = s1*(1.f/524288.f);
    float var = s2v*(1.f/524288.f) - mu*mu;
    float istd = rsqrtf(var + 1e-5f);

    const float* base = qkv + (size_t)n*512*LSEQ;
    int i_ = tid>>4, j_ = tid&15;
    float Mij = 0.f;
    float skp = 0.f;

    for(int m0=0;m0<1024;m0+=256){
        #pragma unroll
        for(int c=0;c<16;c++){
            int ch = 128 + h*16 + c;
            float x = base[(size_t)ch*LSEQ + m0 + tid];
            Ks[c*260+tid] = (x-mu)*istd*gq_w[ch]+gq_b[ch];
        }
        __syncthreads();
        for(int mm=0;mm<256;mm++)
            Mij += Ks[i_*260+mm]*Ks[j_*260+mm];
        if (tid<16){
            for(int mm=0;mm<256;mm++) skp += Ks[tid*260+mm];
        }
        __syncthreads();
    }
    Ml[tid] = Mij;
    if(tid<16){ sumk[tid]=skp; sumq[tid]=0.f; }
    __syncthreads();

    double S2p = 0.0;
    float sqp[16];
    #pragma unroll
    for(int c=0;c<16;c++) sqp[c]=0.f;

    for(int m0=0;m0<1024;m0+=256){
        #pragma unroll
        for(int c=0;c<16;c++){
            int ch = h*16 + c;
            float x = base[(size_t)ch*LSEQ + m0 + tid];
            Ks[c*260+tid] = (x-mu)*istd*gq_w[ch]+gq_b[ch];
        }
        __syncthreads();
        float q[16];
        #pragma unroll
        for(int c=0;c<16;c++) q[c]=Ks[c*260+tid];
        float accf = 0.f;
        #pragma unroll
        for(int i=0;i<16;i++){
            float t=0.f;
            #pragma unroll
            for(int j=0;j<16;j++) t += Ml[i*16+j]*q[j];
            accf += t*q[i];
        }
        S2p += (double)accf;
        #pragma unroll
        for(int c=0;c<16;c++) sqp[c]+=q[c];
        __syncthreads();
    }
    #pragma unroll
    for(int c=0;c<16;c++) atomicAdd(&sumq[c], sqp[c]);
    dred[tid] = S2p;
    __syncthreads();
    for(int s=128;s>0;s>>=1){
        if(tid<s) dred[tid]+=dred[tid+s];
        __syncthreads();
    }
    if(tid==0){
        double S1=0.0;
        for(int c=0;c<16;c++) S1 += (double)sumq[c]*(double)sumk[c];
        double cnt = 1048576.0;
        double mean = S1/cnt;
        double v2 = dred[0]/cnt - mean*mean;
        if(v2 < 0.0) v2 = 0.0;
        istd_head[head] = (float)(1.0/sqrt(v2 + 1e-5));
    }
}

// ---------------------------------------------------------------------------
// Attention v3: single main pass with Cauchy-Schwarz shift bound
// (softmax is shift-exact; only underflow matters, slack is a few sigma).
// 512-thr block = (head, 128 rows). 16-lane group owns 4 rows:
//   dot phase: lane = one of 16 m-slots, computes p[4] (no duplicated dots)
//   PV phase: lane = (qq,dq) accumulates dims dq*8..+7 for m-slots qq*4..+3,
//             p obtained via __shfl (register exchange, no LDS).
// Registers: q[4][16] + o[4][8] ~= 150 VGPR -> no spill (8-wave block caps 256).
// ---------------------------------------------------------------------------
__global__ __launch_bounds__(512) void attn_kernel(
    const float* __restrict__ qkv,
    const float* __restrict__ s_qkv,
    const float* __restrict__ gq_w, const float* __restrict__ gq_b,
    const float* __restrict__ istd_head,
    float* __restrict__ out,
    float* __restrict__ out_stats)
{
    __shared__ float Kc[256*20];   // 16 data + pad (row-major [m][c])
    __shared__ float Vc[256*36];   // 32 data + pad (row-major [m][d])
    __shared__ float sred[8];

    int b = blockIdx.x;
    int head = b>>3, rb = b&7;
    int n = head>>3, h = head&7;
    int tid = threadIdx.x;
    int rg = tid>>4, lane4 = tid&15;
    int qq = lane4&3, dq = lane4>>2;
    int l0 = rb*128;
    int lr = l0 + rg*4;
    int lane = tid&63;
    int gbase = lane&48;

    const float* base = qkv + (size_t)n*512*LSEQ;
    float s1 = s_qkv[2*n], s2v = s_qkv[2*n+1];
    float mu  = s1*(1.f/524288.f);
    float var = s2v*(1.f/524288.f) - mu*mu;
    float istd = rsqrtf(var + 1e-5f);
    float ih = istd_head[head];

    // q fragments, ih folded in; accumulate row norms for the bound
    float q[4][16];
    float qn2[4] = {0.f,0.f,0.f,0.f};
    #pragma unroll
    for(int c=0;c<16;c++){
        int ch = h*16+c;
        float w_ = gq_w[ch]*istd*ih, b_ = (gq_b[ch]-mu*istd*gq_w[ch])*ih;
        #pragma unroll
        for(int r=0;r<4;r++){
            float x = base[(size_t)ch*LSEQ + lr + r];
            float qv = x*w_ + b_;
            q[r][c] = qv;
            qn2[r] += qv*qv;
        }
    }

    // K max-norm prepass (2 rows/thread)
    float kn2max = 0.f;
    for(int mr=tid; mr<1024; mr+=512){
        float s = 0.f;
        #pragma unroll
        for(int c=0;c<16;c++){
            int ch = 128+h*16+c;
            float x = base[(size_t)ch*LSEQ + mr];
            float kv = (x-mu)*istd*gq_w[ch]+gq_b[ch];
            s += kv*kv;
        }
        kn2max = fmaxf(kn2max, s);
    }
    #pragma unroll
    for(int d=1; d<64; d<<=1) kn2max = fmaxf(kn2max, __shfl_xor(kn2max,d));
    if(lane==0) sred[tid>>6] = kn2max;
    __syncthreads();
    float km = sred[0];
    #pragma unroll
    for(int w=1;w<8;w++) km = fmaxf(km, sred[w]);
    float kmax = sqrtf(km);
    float bound[4];
    #pragma unroll
    for(int r=0;r<4;r++) bound[r] = sqrtf(qn2[r])*kmax;

    float o[4][8];
    #pragma unroll
    for(int r=0;r<4;r++)
        #pragma unroll
        for(int d=0;d<8;d++) o[r][d]=0.f;
    float ssum[4] = {0.f,0.f,0.f,0.f};

    for(int m0=0;m0<1024;m0+=256){
        if(tid<256){
            #pragma unroll
            for(int c=0;c<16;c++){
                int ch = 128+h*16+c;
                float x = base[(size_t)ch*LSEQ + m0 + tid];
                Kc[tid*20+c] = (x-mu)*istd*gq_w[ch]+gq_b[ch];
            }
        }
        {
            int vrow = tid&255, dh = (tid>>8)<<4;
            #pragma unroll
            for(int dd=0;dd<16;dd++){
                int ch = 256+h*32+dh+dd;
                float x = base[(size_t)ch*LSEQ + m0 + vrow];
                Vc[vrow*36+dh+dd] = (x-mu)*istd*gq_w[ch]+gq_b[ch];
            }
        }
        __syncthreads();

        for(int j=0;j<16;j++){
            int mm = lane4 + j*16;
            int m = m0 + mm;
            const float4* k4 = (const float4*)(Kc + mm*20);
            float4 k0=k4[0],k1=k4[1],k2=k4[2],k3=k4[3];
            float p[4];
            #pragma unroll
            for(int r=0;r<4;r++){
                float s = q[r][0]*k0.x+q[r][1]*k0.y+q[r][2]*k0.z+q[r][3]*k0.w
                        + q[r][4]*k1.x+q[r][5]*k1.y+q[r][6]*k1.z+q[r][7]*k1.w
                        + q[r][8]*k2.x+q[r][9]*k2.y+q[r][10]*k2.z+q[r][11]*k2.w
                        + q[r][12]*k3.x+q[r][13]*k3.y+q[r][14]*k3.z+q[r][15]*k3.w;
                float pv = __expf(s - bound[r]);
                pv = (m == lr+r) ? 0.f : pv;
                p[r] = pv;
                ssum[r] += pv;
            }
            #pragma unroll
            for(int i=0;i<4;i++){
                int ml = qq*4 + i;
                int src = gbase + ml;
                float pr0 = __shfl(p[0], src);
                float pr1 = __shfl(p[1], src);
                float pr2 = __shfl(p[2], src);
                float pr3 = __shfl(p[3], src);
                const float4* vv = (const float4*)(Vc + (ml + j*16)*36 + dq*8);
                float4 va = vv[0], vb = vv[1];
                o[0][0]+=pr0*va.x; o[0][1]+=pr0*va.y; o[0][2]+=pr0*va.z; o[0][3]+=pr0*va.w;
                o[0][4]+=pr0*vb.x; o[0][5]+=pr0*vb.y; o[0][6]+=pr0*vb.z; o[0][7]+=pr0*vb.w;
                o[1][0]+=pr1*va.x; o[1][1]+=pr1*va.y; o[1][2]+=pr1*va.z; o[1][3]+=pr1*va.w;
                o[1][4]+=pr1*vb.x; o[1][5]+=pr1*vb.y; o[1][6]+=pr1*vb.z; o[1][7]+=pr1*vb.w;
                o[2][0]+=pr2*va.x; o[2][1]+=pr2*va.y; o[2][2]+=pr2*va.z; o[2][3]+=pr2*va.w;
                o[2][4]+=pr2*vb.x; o[2][5]+=pr2*vb.y; o[2][6]+=pr2*vb.z; o[2][7]+=pr2*vb.w;
                o[3][0]+=pr3*va.x; o[3][1]+=pr3*va.y; o[3][2]+=pr3*va.z; o[3][3]+=pr3*va.w;
                o[3][4]+=pr3*vb.x; o[3][5]+=pr3*vb.y; o[3][6]+=pr3*vb.z; o[3][7]+=pr3*vb.w;
            }
        }
        __syncthreads();
    }

    // ssum: every lane covered distinct m-slots -> reduce over all 4 lane bits
    #pragma unroll
    for(int r=0;r<4;r++){
        ssum[r] += __shfl_xor(ssum[r],1);
        ssum[r] += __shfl_xor(ssum[r],2);
        ssum[r] += __shfl_xor(ssum[r],4);
        ssum[r] += __shfl_xor(ssum[r],8);
    }
    // o: partials across qq (lane bits 0,1)
    #pragma unroll
    for(int r=0;r<4;r++)
        #pragma unroll
        for(int d=0;d<8;d++){
            float t = o[r][d];
            t += __shfl_xor(t,1);
            t += __shfl_xor(t,2);
            o[r][d] = t;
        }

    float* osm = Kc;   // 128*33 floats < 5120, free after barrier above
    if(qq==0){
        #pragma unroll
        for(int r=0;r<4;r++){
            float iv = 1.f/ssum[r];
            #pragma unroll
            for(int dd=0;dd<8;dd++)
                osm[(rg*4+r)*33 + dq*8+dd] = o[r][dd]*iv;
        }
    }
    __syncthreads();

    float lsum=0.f, lsq=0.f;
    #pragma unroll
    for(int t=0;t<8;t++){
        int idx = t*512 + tid;
        int d = idx>>7, ll = idx&127;
        float y = osm[ll*33 + d];
        out[(size_t)n*262144 + (size_t)(h*32+d)*LSEQ + l0+ll] = y;
        lsum += y; lsq += y*y;
    }
    float* red = Vc;
    red[tid]=lsum; red[512+tid]=lsq;
    __syncthreads();
    for(int s=256;s>0;s>>=1){
        if(tid<s){ red[tid]+=red[tid+s]; red[512+tid]+=red[512+tid+s]; }
        __syncthreads();
    }
    if(tid==0){
        atomicAdd(&out_stats[2*n],   red[0]);
        atomicAdd(&out_stats[2*n+1], red[512]);
    }
}

// ---------------------------------------------------------------------------
// out = gelu(resid + groupnorm(x)) elementwise; c = channel of element.
// ---------------------------------------------------------------------------
__global__ __launch_bounds__(256) void ew_resid(
    const float* __restrict__ resid, const float* __restrict__ x,
    const float* __restrict__ stats,
    const float* __restrict__ gw, const float* __restrict__ gb,
    float cnt_inv, float* __restrict__ out)
{
    int idx = blockIdx.x*256 + threadIdx.x;   // float4 index
    int n = idx >> 16;                        // 65536 float4 per sample
    int c = (idx >> 8) & 255;
    float ss = stats[2*n], s2 = stats[2*n+1];
    float mu = ss*cnt_inv;
    float var = s2*cnt_inv - mu*mu;
    float istd = rsqrtf(var + 1e-5f);
    float w_ = gw[c], b_ = gb[c];
    float4 xv = ((const float4*)x)[idx];
    float4 rv = ((const float4*)resid)[idx];
    float4 ov;
    ov.x = gelu_f(rv.x + ((xv.x-mu)*istd*w_+b_));
    ov.y = gelu_f(rv.y + ((xv.y-mu)*istd*w_+b_));
    ov.z = gelu_f(rv.z + ((xv.z-mu)*istd*w_+b_));
    ov.w = gelu_f(rv.w + ((xv.w-mu)*istd*w_+b_));
    ((float4*)out)[idx] = ov;
}

// ---------------------------------------------------------------------------
extern "C" void kernel_launch(void* const* d_in, const int* in_sizes, int n_in,
                              void* d_out, int out_size, void* d_ws, size_t ws_size,
                              hipStream_t stream) {
    const float* f     = (const float*)d_in[0];
    const float* w_z   = (const float*)d_in[1];
    const float* gz_w  = (const float*)d_in[2];
    const float* gz_b  = (const float*)d_in[3];
    const float* w_qkv = (const float*)d_in[4];
    const float* gq_w  = (const float*)d_in[5];
    const float* gq_b  = (const float*)d_in[6];
    const float* w_out = (const float*)d_in[7];
    const float* go_w  = (const float*)d_in[8];
    const float* go_b  = (const float*)d_in[9];
    const float* w_f1  = (const float*)d_in[10];
    const float* g1_w  = (const float*)d_in[11];
    const float* g1_b  = (const float*)d_in[12];
    const float* w_f2  = (const float*)d_in[13];
    const float* g2_w  = (const float*)d_in[14];
    const float* g2_b  = (const float*)d_in[15];

    float* ws = (float*)d_ws;
    float* stats = ws;                 // 256 floats
    float* s_z    = stats + 0;
    float* s_qkv  = stats + 16;
    float* s_attn = stats + 32;
    float* s_x    = stats + 48;
    float* s_h1   = stats + 64;
    float* s_h2   = stats + 80;
    float* istdh  = stats + 96;        // 64
    const size_t SM = (size_t)256*1024;   // per-sample 256-ch tensor
    float* buf0 = ws + 256;            // 8*SM  : z0 -> attn_out -> f1 (buf3 alias)
    float* buf1 = buf0 + 8*SM;         // 8*2SM : qkv -> h1pre
    float* buf2 = buf1 + 16*SM;        // 8*SM  : x -> h2pre
    float* buf3 = buf0;                // f1 aliases buf0 (dead after K4)
    float* outp = (float*)d_out;

    hipMemsetAsync(stats, 0, 256*sizeof(float), stream);

    dim3 blk(256);
    // z0 = w_z @ gelu(f)
    gemm_fused<<<dim3(16,4,8),blk,0,stream>>>(w_z, f, buf0,
        nullptr, nullptr, nullptr, 0.f, 1, 256, 256, s_z);
    // qkv = w_qkv @ gelu(gn(z0))
    gemm_fused<<<dim3(16,8,8),blk,0,stream>>>(w_qkv, buf0, buf1,
        s_z, gz_w, gz_b, 1.f/262144.f, 1, 512, 256, s_qkv);
    // analytic per-head logit-LN istd
    head_stats<<<64,blk,0,stream>>>(buf1, s_qkv, gq_w, gq_b, istdh);
    // attention -> attn_out (overwrites z0)
    attn_kernel<<<512,dim3(512),0,stream>>>(buf1, s_qkv, gq_w, gq_b, istdh, buf0, s_attn);
    // x = w_out @ gelu(ln(attn_out))
    gemm_fused<<<dim3(16,4,8),blk,0,stream>>>(w_out, buf0, buf2,
        s_attn, nullptr, nullptr, 1.f/262144.f, 1, 256, 256, s_x);
    // f1 = gelu(f + gn_go(x))   (writes over attn_out region)
    ew_resid<<<2048,blk,0,stream>>>(f, buf2, s_x, go_w, go_b, 1.f/262144.f, buf3);
    // h1 = w_ffn1 @ f1
    gemm_fused<<<dim3(16,8,8),blk,0,stream>>>(w_f1, buf3, buf1,
        nullptr, nullptr, nullptr, 0.f, 0, 512, 256, s_h1);
    // h2 = w_ffn2 @ gelu(gn_g1(h1))
    gemm_fused<<<dim3(16,4,8),blk,0,stream>>>(w_f2, buf1, buf2,
        s_h1, g1_w, g1_b, 1.f/524288.f, 1, 256, 512, s_h2);
    // out = gelu(f1 + gn_g2(h2))
    ew_resid<<<2048,blk,0,stream>>>(buf3, buf2, s_h2, g2_w, g2_b, 1.f/262144.f, outp);
}